// Round 6
// baseline (3725.349 us; speedup 1.0000x reference)
//
#include <hip/hip_runtime.h>
#include <hip/hip_fp16.h>

// DeductronCTC v6: single-pass fused kernel with decoupled-lookback scan.
//   K0: pre-pack WL|WR and W_logit into MFMA fragment layout (f16) in ws.
//   KF: per 64-row chunk (ticket-ordered): X -> fp16 MFMA -> sigmoid -> a,b
//       in registers -> chunk aggregate -> publish(agg) -> lookback compose
//       exclusive prefix -> publish(inclusive) -> z gen -> logits MFMA -> out.
// Flags/counter reset via hipMemsetAsync each launch (graph-capturable).
// Ticket guarantees predecessors are resident -> lookback cannot deadlock.

constexpr int NF  = 500000;
constexpr int KIN = 128;
constexpr int M   = 64;
constexpr int CH  = 64;
constexpr int NC  = (NF + CH - 1) / CH;   // 7813

typedef _Float16 f16x8 __attribute__((ext_vector_type(8)));
typedef float    f32x4 __attribute__((ext_vector_type(4)));

__device__ __forceinline__ float sig(float x) { return 1.0f / (1.0f + __expf(-x)); }

// ---------------------------------------------------------------- K0
__global__ void k0_pack(const float* __restrict__ WL, const float* __restrict__ WR,
                        const float* __restrict__ WLog,
                        _Float16* __restrict__ wpre, _Float16* __restrict__ wlogpre)
{
    int flat = blockIdx.x * 1024 + threadIdx.x * 4;
    if (flat < 16384) {
        int k = flat >> 7, col = flat & 127;
        float4 v = (col < 64) ? *(const float4*)&WL[k * 64 + col]
                              : *(const float4*)&WR[k * 64 + (col - 64)];
        int kb = k >> 3, kj = k & 7;
        wpre[(kb * 128 + col + 0) * 8 + kj] = (_Float16)v.x;
        wpre[(kb * 128 + col + 1) * 8 + kj] = (_Float16)v.y;
        wpre[(kb * 128 + col + 2) * 8 + kj] = (_Float16)v.z;
        wpre[(kb * 128 + col + 3) * 8 + kj] = (_Float16)v.w;
    } else if (flat < 16384 + 4096) {
        int f2 = flat - 16384;
        int k = f2 >> 6, c = f2 & 63;
        float4 v = *(const float4*)&WLog[f2];
        int kb = k >> 3, kj = k & 7;
        wlogpre[(kb * 64 + c + 0) * 8 + kj] = (_Float16)v.x;
        wlogpre[(kb * 64 + c + 1) * 8 + kj] = (_Float16)v.y;
        wlogpre[(kb * 64 + c + 2) * 8 + kj] = (_Float16)v.z;
        wlogpre[(kb * 64 + c + 3) * 8 + kj] = (_Float16)v.w;
    }
}

// MFMA + a,b + per-wave inclusive kb-scan (identical math to v5, verified).
#define COMPUTE_AB()                                                          \
    f32x4 acc[8];                                                             \
    _Pragma("unroll")                                                         \
    for (int c = 0; c < 8; ++c) acc[c] = (f32x4){0.f, 0.f, 0.f, 0.f};         \
    {                                                                         \
        const int xrow = t0 + w * 16 + arow;                                  \
        const float* xp = X + (size_t)xrow * KIN;                             \
        const bool rowok = xrow < NF;                                         \
        _Pragma("unroll")                                                     \
        for (int s = 0; s < 4; ++s) {                                         \
            f32x4 v0 = (f32x4){0.f,0.f,0.f,0.f}, v1 = v0;                     \
            if (rowok) {                                                      \
                v0 = *(const f32x4*)&xp[s * 32 + kb * 8];                     \
                v1 = *(const f32x4*)&xp[s * 32 + kb * 8 + 4];                 \
            }                                                                 \
            f16x8 af = { (_Float16)v0.x, (_Float16)v0.y, (_Float16)v0.z,      \
                         (_Float16)v0.w, (_Float16)v1.x, (_Float16)v1.y,      \
                         (_Float16)v1.z, (_Float16)v1.w };                    \
            _Pragma("unroll")                                                 \
            for (int c = 0; c < 8; ++c) {                                     \
                f16x8 bf = *(const f16x8*)&wpre[((s*4+kb)*128 + c*16 + arow)*8]; \
                acc[c] = __builtin_amdgcn_mfma_f32_16x16x32_f16(af, bf, acc[c], 0, 0, 0); \
            }                                                                 \
        }                                                                     \
    }                                                                         \
    float a[4][4], b[4][4];                                                   \
    _Pragma("unroll")                                                         \
    for (int c = 0; c < 4; ++c) {                                             \
        float blv = bL[c * 16 + arow], brv = bR[c * 16 + arow];               \
        _Pragma("unroll")                                                     \
        for (int reg = 0; reg < 4; ++reg) {                                   \
            float lv = sig(acc[c][reg] + blv);                                \
            float rv = sig(acc[c + 4][reg] + brv);                            \
            a[c][reg] = lv * rv;                                              \
            b[c][reg] = 1.0f - lv;                                            \
        }                                                                     \
    }                                                                         \
    float Ai[4], Bi[4];                                                       \
    _Pragma("unroll")                                                         \
    for (int c = 0; c < 4; ++c) {                                             \
        float A = 1.f, B = 0.f;                                               \
        _Pragma("unroll")                                                     \
        for (int reg = 0; reg < 4; ++reg) {                                   \
            if (t0 + w * 16 + kb * 4 + reg < NF - 1) {                        \
                B = fmaf(a[c][reg], B, b[c][reg]);                            \
                A *= a[c][reg];                                               \
            }                                                                 \
        }                                                                     \
        Ai[c] = A; Bi[c] = B;                                                 \
    }                                                                         \
    _Pragma("unroll")                                                         \
    for (int d = 16; d < 64; d <<= 1) {                                       \
        _Pragma("unroll")                                                     \
        for (int c = 0; c < 4; ++c) {                                         \
            float pA = __shfl_up(Ai[c], d), pB = __shfl_up(Bi[c], d);         \
            if (lane >= d) { Bi[c] = fmaf(Ai[c], pB, Bi[c]); Ai[c] *= pA; }   \
        }                                                                     \
    }

// ---------------------------------------------------------------- fused
__global__ __launch_bounds__(256, 4)
void k_fused(const float* __restrict__ X, const _Float16* __restrict__ wpre,
             const _Float16* __restrict__ wlogpre,
             const float* __restrict__ bL, const float* __restrict__ bR,
             const float* __restrict__ bLog,
             int* __restrict__ flags, int* __restrict__ counter,
             float* __restrict__ aggA, float* __restrict__ aggB,
             float* __restrict__ incA, float* __restrict__ incB,
             float* __restrict__ out)
{
    __shared__ float pA_s[256], pB_s[256];
    __shared__ float u_s[64];
    __shared__ _Float16 z_s[64 * 72];
    __shared__ int c_sh;

    const int tid = threadIdx.x, lane = tid & 63, w = tid >> 6;
    const int arow = lane & 15, kb = lane >> 4;

    if (tid == 0) c_sh = atomicAdd(counter, 1);   // ticket = logical chunk
    __syncthreads();
    const int cid = c_sh;
    const int t0  = cid * CH;

    COMPUTE_AB();

    // exclusive kb-prefix within wave (transform wave-start -> lane's rows)
    float eA[4], eB[4];
    #pragma unroll
    for (int c = 0; c < 4; ++c) {
        eA[c] = __shfl_up(Ai[c], 16);
        eB[c] = __shfl_up(Bi[c], 16);
        if (kb == 0) { eA[c] = 1.f; eB[c] = 0.f; }
    }
    if (kb == 3) {   // wave totals
        #pragma unroll
        for (int c = 0; c < 4; ++c) {
            pA_s[w * 64 + c * 16 + arow] = Ai[c];
            pB_s[w * 64 + c * 16 + arow] = Bi[c];
        }
    }
    __syncthreads();

    // ---- wave 0: block aggregate, publish, lookback, publish inclusive
    if (w == 0) {
        const int j = lane;
        float At = 1.f, Bt = 0.f;
        #pragma unroll
        for (int s2 = 0; s2 < 4; ++s2) {
            float qa = pA_s[s2 * 64 + j], qb = pB_s[s2 * 64 + j];
            Bt = fmaf(qa, Bt, qb);
            At *= qa;
        }
        aggA[(size_t)cid * 64 + j] = At;
        aggB[(size_t)cid * 64 + j] = Bt;
        __threadfence();
        if (lane == 0)
            __hip_atomic_store(&flags[cid], 1, __ATOMIC_RELEASE, __HIP_MEMORY_SCOPE_AGENT);

        // lookback: compose exclusive prefix E = T_{cid-1} o ... o T_0
        float Ar = 1.f, Br = 0.f;
        int p = cid - 1;
        while (p >= 0) {
            int fl;
            do {
                fl = __hip_atomic_load(&flags[p], __ATOMIC_ACQUIRE, __HIP_MEMORY_SCOPE_AGENT);
            } while (fl == 0);
            if (fl == 2) {
                float pa = incA[(size_t)p * 64 + j], pb = incB[(size_t)p * 64 + j];
                Br = fmaf(Ar, pb, Br); Ar *= pa;
                break;
            } else {
                float pa = aggA[(size_t)p * 64 + j], pb = aggB[(size_t)p * 64 + j];
                Br = fmaf(Ar, pb, Br); Ar *= pa;
                --p;
            }
        }
        u_s[j] = Br;                       // u_start = E(0) = Br
        incA[(size_t)cid * 64 + j] = At * Ar;
        incB[(size_t)cid * 64 + j] = fmaf(At, Br, Bt);
        __threadfence();
        if (lane == 0)
            __hip_atomic_store(&flags[cid], 2, __ATOMIC_RELEASE, __HIP_MEMORY_SCOPE_AGENT);
    }
    __syncthreads();

    // ---- compose chunk-start state through prior waves
    float u[4];
    #pragma unroll
    for (int c = 0; c < 4; ++c) u[c] = u_s[c * 16 + arow];
    for (int s2 = 0; s2 < w; ++s2) {
        #pragma unroll
        for (int c = 0; c < 4; ++c) {
            float qa = pA_s[s2 * 64 + c * 16 + arow];
            float qb = pB_s[s2 * 64 + c * 16 + arow];
            u[c] = fmaf(qa, u[c], qb);
        }
    }
    // ---- z for own rows (z_t = state BEFORE transform t)
    #pragma unroll
    for (int c = 0; c < 4; ++c) {
        float uk = fmaf(eA[c], u[c], eB[c]);
        #pragma unroll
        for (int reg = 0; reg < 4; ++reg) {
            z_s[(w * 16 + kb * 4 + reg) * 72 + c * 16 + arow] = (_Float16)uk;
            if (t0 + w * 16 + kb * 4 + reg < NF - 1)
                uk = fmaf(a[c][reg], uk, b[c][reg]);
        }
    }
    __syncthreads();

    // ---- logits MFMA: wave w -> rows [w*16, +16)
    f32x4 acc2[4];
    #pragma unroll
    for (int ct = 0; ct < 4; ++ct) acc2[ct] = (f32x4){0.f, 0.f, 0.f, 0.f};
    #pragma unroll
    for (int ks = 0; ks < 2; ++ks) {
        f16x8 af = *(const f16x8*)&z_s[(w * 16 + arow) * 72 + ks * 32 + kb * 8];
        #pragma unroll
        for (int ct = 0; ct < 4; ++ct) {
            f16x8 bf = *(const f16x8*)&wlogpre[((ks * 4 + kb) * 64 + ct * 16 + arow) * 8];
            acc2[ct] = __builtin_amdgcn_mfma_f32_16x16x32_f16(af, bf, acc2[ct], 0, 0, 0);
        }
    }
    #pragma unroll
    for (int ct = 0; ct < 4; ++ct) {
        float bv = bLog[ct * 16 + arow];
        #pragma unroll
        for (int reg = 0; reg < 4; ++reg) {
            int t = t0 + w * 16 + kb * 4 + reg;
            if (t < NF) out[t * M + ct * 16 + arow] = acc2[ct][reg] + bv;
        }
    }
}

// ---------------------------------------------------------------- host
extern "C" void kernel_launch(void* const* d_in, const int* in_sizes, int n_in,
                              void* d_out, int out_size, void* d_ws, size_t ws_size,
                              hipStream_t stream)
{
    const float* X    = (const float*)d_in[0];
    const float* WL   = (const float*)d_in[2];
    const float* bL   = (const float*)d_in[3];
    const float* WR   = (const float*)d_in[4];
    const float* bR   = (const float*)d_in[5];
    const float* WLog = (const float*)d_in[6];
    const float* bLog = (const float*)d_in[7];

    // ws layout (ints/floats; 1 GB available, we use ~8.1 MB)
    int*   flags   = (int*)d_ws;                  // [NC]
    int*   counter = flags + NC;                  // [1]
    float* aggA    = (float*)d_ws + 8192;         // [NC*64] each
    float* aggB    = aggA + (size_t)NC * 64;
    float* incA    = aggB + (size_t)NC * 64;
    float* incB    = incA + (size_t)NC * 64;
    _Float16* wpre    = (_Float16*)(incB + (size_t)NC * 64);  // 16384 halfs
    _Float16* wlogpre = wpre + 16384;                          // 4096 halfs

    // reset flags + counter every call (graph-capturable memset node)
    hipMemsetAsync(flags, 0, (NC + 1) * sizeof(int), stream);

    k0_pack<<<20, 256, 0, stream>>>(WL, WR, WLog, wpre, wlogpre);
    k_fused<<<NC, 256, 0, stream>>>(X, wpre, wlogpre, bL, bR, bLog,
                                    flags, counter, aggA, aggB, incA, incB,
                                    (float*)d_out);
}

// Round 7
// 218.311 us; speedup vs baseline: 17.0644x; 17.0644x over previous
//
#include <hip/hip_runtime.h>
#include <hip/hip_fp16.h>

// DeductronCTC v7 (3-kernel, prefix-store):
//   K0: pre-pack WL|WR and W_logit into MFMA fragment layout (f16) in ws.
//   K1: X -> fp16 MFMA -> sigmoid -> a,b (regs) -> per-row chunk-exclusive
//       prefix transforms (PA,PB) stored as __half2 (128 MB in ws) +
//       chunk summaries sA,sB. Chains stay f32 in registers.
//   K3: 2-level scan of chunk summaries -> u0 (chunk-start states).
//   K4: z = PA*u0 + PB (1 fma/elem, no serial chain), logits MFMA -> out.
// Replay-safe: no buffer both read+written by a kernel, no aliasing, no
// cross-block spin. No memset needed.

constexpr int NF  = 500000;
constexpr int KIN = 128;
constexpr int M   = 64;
constexpr int CH  = 64;
constexpr int NC  = (NF + CH - 1) / CH;   // 7813
constexpr int NG  = (NC + 63) / 64;       // 123
constexpr int GPW = (NG + 3) / 4;         // 31

typedef _Float16 f16x8 __attribute__((ext_vector_type(8)));
typedef float    f32x4 __attribute__((ext_vector_type(4)));

__device__ __forceinline__ float sig(float x) { return 1.0f / (1.0f + __expf(-x)); }

// ---------------------------------------------------------------- K0
__global__ void k0_pack(const float* __restrict__ WL, const float* __restrict__ WR,
                        const float* __restrict__ WLog,
                        _Float16* __restrict__ wpre, _Float16* __restrict__ wlogpre)
{
    int flat = blockIdx.x * 1024 + threadIdx.x * 4;
    if (flat < 16384) {
        int k = flat >> 7, col = flat & 127;
        float4 v = (col < 64) ? *(const float4*)&WL[k * 64 + col]
                              : *(const float4*)&WR[k * 64 + (col - 64)];
        int kb = k >> 3, kj = k & 7;
        wpre[(kb * 128 + col + 0) * 8 + kj] = (_Float16)v.x;
        wpre[(kb * 128 + col + 1) * 8 + kj] = (_Float16)v.y;
        wpre[(kb * 128 + col + 2) * 8 + kj] = (_Float16)v.z;
        wpre[(kb * 128 + col + 3) * 8 + kj] = (_Float16)v.w;
    } else if (flat < 16384 + 4096) {
        int f2 = flat - 16384;
        int k = f2 >> 6, c = f2 & 63;
        float4 v = *(const float4*)&WLog[f2];
        int kb = k >> 3, kj = k & 7;
        wlogpre[(kb * 64 + c + 0) * 8 + kj] = (_Float16)v.x;
        wlogpre[(kb * 64 + c + 1) * 8 + kj] = (_Float16)v.y;
        wlogpre[(kb * 64 + c + 2) * 8 + kj] = (_Float16)v.z;
        wlogpre[(kb * 64 + c + 3) * 8 + kj] = (_Float16)v.w;
    }
}

// MFMA + a,b + per-wave inclusive kb-scan (verified in v5).
#define COMPUTE_AB()                                                          \
    f32x4 acc[8];                                                             \
    _Pragma("unroll")                                                         \
    for (int c = 0; c < 8; ++c) acc[c] = (f32x4){0.f, 0.f, 0.f, 0.f};         \
    {                                                                         \
        const int xrow = t0 + w * 16 + arow;                                  \
        const float* xp = X + (size_t)xrow * KIN;                             \
        const bool rowok = xrow < NF;                                         \
        _Pragma("unroll")                                                     \
        for (int s = 0; s < 4; ++s) {                                         \
            f32x4 v0 = (f32x4){0.f,0.f,0.f,0.f}, v1 = v0;                     \
            if (rowok) {                                                      \
                v0 = *(const f32x4*)&xp[s * 32 + kb * 8];                     \
                v1 = *(const f32x4*)&xp[s * 32 + kb * 8 + 4];                 \
            }                                                                 \
            f16x8 af = { (_Float16)v0.x, (_Float16)v0.y, (_Float16)v0.z,      \
                         (_Float16)v0.w, (_Float16)v1.x, (_Float16)v1.y,      \
                         (_Float16)v1.z, (_Float16)v1.w };                    \
            _Pragma("unroll")                                                 \
            for (int c = 0; c < 8; ++c) {                                     \
                f16x8 bf = *(const f16x8*)&wpre[((s*4+kb)*128 + c*16 + arow)*8]; \
                acc[c] = __builtin_amdgcn_mfma_f32_16x16x32_f16(af, bf, acc[c], 0, 0, 0); \
            }                                                                 \
        }                                                                     \
    }                                                                         \
    float a[4][4], b[4][4];                                                   \
    _Pragma("unroll")                                                         \
    for (int c = 0; c < 4; ++c) {                                             \
        float blv = bL[c * 16 + arow], brv = bR[c * 16 + arow];               \
        _Pragma("unroll")                                                     \
        for (int reg = 0; reg < 4; ++reg) {                                   \
            float lv = sig(acc[c][reg] + blv);                                \
            float rv = sig(acc[c + 4][reg] + brv);                            \
            a[c][reg] = lv * rv;                                              \
            b[c][reg] = 1.0f - lv;                                            \
        }                                                                     \
    }                                                                         \
    float Ai[4], Bi[4];                                                       \
    _Pragma("unroll")                                                         \
    for (int c = 0; c < 4; ++c) {                                             \
        float A = 1.f, B = 0.f;                                               \
        _Pragma("unroll")                                                     \
        for (int reg = 0; reg < 4; ++reg) {                                   \
            if (t0 + w * 16 + kb * 4 + reg < NF - 1) {                        \
                B = fmaf(a[c][reg], B, b[c][reg]);                            \
                A *= a[c][reg];                                               \
            }                                                                 \
        }                                                                     \
        Ai[c] = A; Bi[c] = B;                                                 \
    }                                                                         \
    _Pragma("unroll")                                                         \
    for (int d = 16; d < 64; d <<= 1) {                                       \
        _Pragma("unroll")                                                     \
        for (int c = 0; c < 4; ++c) {                                         \
            float pA = __shfl_up(Ai[c], d), pB = __shfl_up(Bi[c], d);         \
            if (lane >= d) { Bi[c] = fmaf(Ai[c], pB, Bi[c]); Ai[c] *= pA; }   \
        }                                                                     \
    }

// ---------------------------------------------------------------- K1
__global__ __launch_bounds__(256, 4)
void k1_prefix(const float* __restrict__ X, const _Float16* __restrict__ wpre,
               const float* __restrict__ bL, const float* __restrict__ bR,
               float* __restrict__ sA, float* __restrict__ sB,
               __half2* __restrict__ pre)
{
    __shared__ float pA_s[256], pB_s[256];
    const int tid = threadIdx.x, lane = tid & 63, w = tid >> 6;
    const int arow = lane & 15, kb = lane >> 4;
    const int t0 = blockIdx.x * CH;

    COMPUTE_AB();

    // exclusive within-wave prefix (transform from wave start to lane's rows)
    float eA[4], eB[4];
    #pragma unroll
    for (int c = 0; c < 4; ++c) {
        eA[c] = __shfl_up(Ai[c], 16);
        eB[c] = __shfl_up(Bi[c], 16);
        if (kb == 0) { eA[c] = 1.f; eB[c] = 0.f; }
    }
    if (kb == 3) {   // wave totals
        #pragma unroll
        for (int c = 0; c < 4; ++c) {
            pA_s[w * 64 + c * 16 + arow] = Ai[c];
            pB_s[w * 64 + c * 16 + arow] = Bi[c];
        }
    }
    __syncthreads();

    // compose prior-wave totals: E = T_{w-1} o ... o T_0 (per column)
    float EA[4] = {1.f, 1.f, 1.f, 1.f}, EB[4] = {0.f, 0.f, 0.f, 0.f};
    for (int s2 = 0; s2 < w; ++s2) {
        #pragma unroll
        for (int c = 0; c < 4; ++c) {
            float qa = pA_s[s2 * 64 + c * 16 + arow];
            float qb = pB_s[s2 * 64 + c * 16 + arow];
            EB[c] = fmaf(qa, EB[c], qb);
            EA[c] *= qa;
        }
    }
    // per-row chunk-exclusive prefix: P_t = (within-wave eA,eB) o E, then
    // walk own 4 rows: emit BEFORE composing row's transform.
    #pragma unroll
    for (int c = 0; c < 4; ++c) {
        float pa = eA[c] * EA[c];
        float pb = fmaf(eA[c], EB[c], eB[c]);
        #pragma unroll
        for (int reg = 0; reg < 4; ++reg) {
            int t = t0 + w * 16 + kb * 4 + reg;
            if (t < NF)
                pre[(size_t)t * 64 + c * 16 + arow] = __floats2half2_rn(pa, pb);
            if (t < NF - 1) {
                pb = fmaf(a[c][reg], pb, b[c][reg]);
                pa *= a[c][reg];
            }
        }
    }
    // chunk summary -> sA,sB
    if (tid < 64) {
        float At = 1.f, Bt = 0.f;
        #pragma unroll
        for (int s2 = 0; s2 < 4; ++s2) {
            float qa = pA_s[s2 * 64 + tid], qb = pB_s[s2 * 64 + tid];
            Bt = fmaf(qa, Bt, qb);
            At *= qa;
        }
        sA[tid * NC + blockIdx.x] = At;
        sB[tid * NC + blockIdx.x] = Bt;
    }
}

// ---------------------------------------------------------------- K3
__global__ __launch_bounds__(256)
void k3_scan(const float* __restrict__ sA, const float* __restrict__ sB,
             float* __restrict__ u0)
{
    __shared__ float tA_s[4], tB_s[4];
    const int j    = blockIdx.x;
    const int lane = threadIdx.x & 63;
    const int w    = threadIdx.x >> 6;

    float PA[GPW], PB[GPW];
    float cA = 1.f, cB = 0.f;
    #pragma unroll
    for (int g = 0; g < GPW; ++g) {
        int c = (w * GPW + g) * 64 + lane;
        float A = 1.f, B = 0.f;
        if (c < NC) { A = sA[j * NC + c]; B = sB[j * NC + c]; }
        #pragma unroll
        for (int d = 1; d < 64; d <<= 1) {
            float pA = __shfl_up(A, d), pB = __shfl_up(B, d);
            if (lane >= d) { B = fmaf(A, pB, B); A *= pA; }
        }
        float eA = __shfl_up(A, 1), eB = __shfl_up(B, 1);
        if (lane == 0) { eA = 1.f; eB = 0.f; }
        PA[g] = eA * cA;
        PB[g] = fmaf(eA, cB, eB);
        float tA = __shfl(A, 63), tB = __shfl(B, 63);
        cB = fmaf(tA, cB, tB);
        cA *= tA;
    }
    if (lane == 0) { tA_s[w] = cA; tB_s[w] = cB; }
    __syncthreads();
    float uw = 0.f;
    for (int s2 = 0; s2 < w; ++s2) uw = fmaf(tA_s[s2], uw, tB_s[s2]);
    #pragma unroll
    for (int g = 0; g < GPW; ++g) {
        int c = (w * GPW + g) * 64 + lane;
        if (c < NC) u0[c * M + j] = fmaf(PA[g], uw, PB[g]);
    }
}

// ---------------------------------------------------------------- K4
// z[t][j] = PA*u0[chunk][j] + PB, then logits MFMA. No serial chain.
__global__ __launch_bounds__(256, 4)
void k4_light(const __half2* __restrict__ pre, const float* __restrict__ u0,
              const _Float16* __restrict__ wlogpre, const float* __restrict__ bLog,
              float* __restrict__ out)
{
    __shared__ _Float16 z_s[64 * 72];
    const int tid = threadIdx.x, lane = tid & 63, w = tid >> 6;
    const int arow = lane & 15, kb = lane >> 4;
    const int t0 = blockIdx.x * CH;

    float u0v[4];
    #pragma unroll
    for (int c = 0; c < 4; ++c) u0v[c] = u0[blockIdx.x * 64 + c * 16 + arow];

    #pragma unroll
    for (int c = 0; c < 4; ++c) {
        #pragma unroll
        for (int reg = 0; reg < 4; ++reg) {
            int rl = w * 16 + kb * 4 + reg;
            int t  = t0 + rl;
            float z = 0.f;
            if (t < NF) {
                __half2 p = pre[(size_t)t * 64 + c * 16 + arow];
                z = fmaf(__low2float(p), u0v[c], __high2float(p));
            }
            z_s[rl * 72 + c * 16 + arow] = (_Float16)z;
        }
    }
    __syncthreads();

    f32x4 acc2[4];
    #pragma unroll
    for (int ct = 0; ct < 4; ++ct) acc2[ct] = (f32x4){0.f, 0.f, 0.f, 0.f};
    #pragma unroll
    for (int ks = 0; ks < 2; ++ks) {
        f16x8 af = *(const f16x8*)&z_s[(w * 16 + arow) * 72 + ks * 32 + kb * 8];
        #pragma unroll
        for (int ct = 0; ct < 4; ++ct) {
            f16x8 bf = *(const f16x8*)&wlogpre[((ks * 4 + kb) * 64 + ct * 16 + arow) * 8];
            acc2[ct] = __builtin_amdgcn_mfma_f32_16x16x32_f16(af, bf, acc2[ct], 0, 0, 0);
        }
    }
    #pragma unroll
    for (int ct = 0; ct < 4; ++ct) {
        float bv = bLog[ct * 16 + arow];
        #pragma unroll
        for (int reg = 0; reg < 4; ++reg) {
            int t = t0 + w * 16 + kb * 4 + reg;
            if (t < NF) out[t * M + ct * 16 + arow] = acc2[ct][reg] + bv;
        }
    }
}

// ---------------------------------------------------------------- host
extern "C" void kernel_launch(void* const* d_in, const int* in_sizes, int n_in,
                              void* d_out, int out_size, void* d_ws, size_t ws_size,
                              hipStream_t stream)
{
    const float* X    = (const float*)d_in[0];
    const float* WL   = (const float*)d_in[2];
    const float* bL   = (const float*)d_in[3];
    const float* WR   = (const float*)d_in[4];
    const float* bR   = (const float*)d_in[5];
    const float* WLog = (const float*)d_in[6];
    const float* bLog = (const float*)d_in[7];

    // ws layout (~134 MB of the 1 GB):
    __half2* pre = (__half2*)d_ws;                         // NF*64 (128 MB)
    float* sA = (float*)d_ws + (size_t)NF * 64;            // 64*NC
    float* sB = sA + (size_t)64 * NC;
    float* u0 = sB + (size_t)64 * NC;
    _Float16* wpre    = (_Float16*)(u0 + (size_t)64 * NC); // 16384 halfs
    _Float16* wlogpre = wpre + 16384;                      // 4096 halfs

    k0_pack<<<20, 256, 0, stream>>>(WL, WR, WLog, wpre, wlogpre);
    k1_prefix<<<NC, 256, 0, stream>>>(X, wpre, bL, bR, sA, sB, pre);
    k3_scan<<<M, 256, 0, stream>>>(sA, sB, u0);
    k4_light<<<NC, 256, 0, stream>>>(pre, u0, wlogpre, bLog, (float*)d_out);
}

// Round 8
// 215.212 us; speedup vs baseline: 17.3101x; 1.0144x over previous
//
#include <hip/hip_runtime.h>
#include <hip/hip_fp16.h>

// DeductronCTC v8 (3-kernel, prefix-store, full occupancy):
//   K0: pre-pack WL|WR and W_logit into MFMA fragment layout (f16) in ws.
//   K1: X -> fp16 MFMA -> sigmoid -> a,b (regs) -> per-row chunk-exclusive
//       prefix transforms (PA,PB) stored as packed f16 pairs, 16B/lane
//       vector stores + chunk summaries sA,sB.
//   K3: 2-level scan of chunk summaries -> u0 (chunk-start states).
//   K4: z = PA*u0 + PB (1 fma/elem), logits MFMA -> out. 16B/lane pre loads.
// pre layout per chunk: [w][kb][c][arow][reg] half2 -> lane's 4 regs are one
// 16B vector. Same mapping in K1 (write) and K4 (read).
// Replay-safe: no buffer both read+written by a kernel, no aliasing.

constexpr int NF  = 500000;
constexpr int KIN = 128;
constexpr int M   = 64;
constexpr int CH  = 64;
constexpr int NC  = (NF + CH - 1) / CH;   // 7813
constexpr int NG  = (NC + 63) / 64;       // 123
constexpr int GPW = (NG + 3) / 4;         // 31

typedef _Float16 f16x8 __attribute__((ext_vector_type(8)));
typedef float    f32x4 __attribute__((ext_vector_type(4)));

__device__ __forceinline__ float sig(float x) {
    return __frcp_rn(1.0f + __expf(-x));   // rcp approx ok: ~2e-7 rel << f16 rounding
}

// ---------------------------------------------------------------- K0
__global__ void k0_pack(const float* __restrict__ WL, const float* __restrict__ WR,
                        const float* __restrict__ WLog,
                        _Float16* __restrict__ wpre, _Float16* __restrict__ wlogpre)
{
    int flat = blockIdx.x * 1024 + threadIdx.x * 4;
    if (flat < 16384) {
        int k = flat >> 7, col = flat & 127;
        float4 v = (col < 64) ? *(const float4*)&WL[k * 64 + col]
                              : *(const float4*)&WR[k * 64 + (col - 64)];
        int kb = k >> 3, kj = k & 7;
        wpre[(kb * 128 + col + 0) * 8 + kj] = (_Float16)v.x;
        wpre[(kb * 128 + col + 1) * 8 + kj] = (_Float16)v.y;
        wpre[(kb * 128 + col + 2) * 8 + kj] = (_Float16)v.z;
        wpre[(kb * 128 + col + 3) * 8 + kj] = (_Float16)v.w;
    } else if (flat < 16384 + 4096) {
        int f2 = flat - 16384;
        int k = f2 >> 6, c = f2 & 63;
        float4 v = *(const float4*)&WLog[f2];
        int kb = k >> 3, kj = k & 7;
        wlogpre[(kb * 64 + c + 0) * 8 + kj] = (_Float16)v.x;
        wlogpre[(kb * 64 + c + 1) * 8 + kj] = (_Float16)v.y;
        wlogpre[(kb * 64 + c + 2) * 8 + kj] = (_Float16)v.z;
        wlogpre[(kb * 64 + c + 3) * 8 + kj] = (_Float16)v.w;
    }
}

// MFMA + a,b + per-wave inclusive kb-scan (verified v5-v7).
#define COMPUTE_AB()                                                          \
    f32x4 acc[8];                                                             \
    _Pragma("unroll")                                                         \
    for (int c = 0; c < 8; ++c) acc[c] = (f32x4){0.f, 0.f, 0.f, 0.f};         \
    {                                                                         \
        const int xrow = t0 + w * 16 + arow;                                  \
        const float* xp = X + (size_t)xrow * KIN;                             \
        const bool rowok = xrow < NF;                                         \
        _Pragma("unroll")                                                     \
        for (int s = 0; s < 4; ++s) {                                         \
            f32x4 v0 = (f32x4){0.f,0.f,0.f,0.f}, v1 = v0;                     \
            if (rowok) {                                                      \
                v0 = *(const f32x4*)&xp[s * 32 + kb * 8];                     \
                v1 = *(const f32x4*)&xp[s * 32 + kb * 8 + 4];                 \
            }                                                                 \
            f16x8 af = { (_Float16)v0.x, (_Float16)v0.y, (_Float16)v0.z,      \
                         (_Float16)v0.w, (_Float16)v1.x, (_Float16)v1.y,      \
                         (_Float16)v1.z, (_Float16)v1.w };                    \
            _Pragma("unroll")                                                 \
            for (int c = 0; c < 8; ++c) {                                     \
                f16x8 bf = *(const f16x8*)&wpre[((s*4+kb)*128 + c*16 + arow)*8]; \
                acc[c] = __builtin_amdgcn_mfma_f32_16x16x32_f16(af, bf, acc[c], 0, 0, 0); \
            }                                                                 \
        }                                                                     \
    }                                                                         \
    float a[4][4], b[4][4];                                                   \
    _Pragma("unroll")                                                         \
    for (int c = 0; c < 4; ++c) {                                             \
        float blv = bL[c * 16 + arow], brv = bR[c * 16 + arow];               \
        _Pragma("unroll")                                                     \
        for (int reg = 0; reg < 4; ++reg) {                                   \
            float lv = sig(acc[c][reg] + blv);                                \
            float rv = sig(acc[c + 4][reg] + brv);                            \
            a[c][reg] = lv * rv;                                              \
            b[c][reg] = 1.0f - lv;                                            \
        }                                                                     \
    }                                                                         \
    float Ai[4], Bi[4];                                                       \
    _Pragma("unroll")                                                         \
    for (int c = 0; c < 4; ++c) {                                             \
        float A = 1.f, B = 0.f;                                               \
        _Pragma("unroll")                                                     \
        for (int reg = 0; reg < 4; ++reg) {                                   \
            if (t0 + w * 16 + kb * 4 + reg < NF - 1) {                        \
                B = fmaf(a[c][reg], B, b[c][reg]);                            \
                A *= a[c][reg];                                               \
            }                                                                 \
        }                                                                     \
        Ai[c] = A; Bi[c] = B;                                                 \
    }                                                                         \
    _Pragma("unroll")                                                         \
    for (int d = 16; d < 64; d <<= 1) {                                       \
        _Pragma("unroll")                                                     \
        for (int c = 0; c < 4; ++c) {                                         \
            float pA = __shfl_up(Ai[c], d), pB = __shfl_up(Bi[c], d);         \
            if (lane >= d) { Bi[c] = fmaf(Ai[c], pB, Bi[c]); Ai[c] *= pA; }   \
        }                                                                     \
    }

// ---------------------------------------------------------------- K1
__global__ __launch_bounds__(256, 8)
void k1_prefix(const float* __restrict__ X, const _Float16* __restrict__ wpre,
               const float* __restrict__ bL, const float* __restrict__ bR,
               float* __restrict__ sA, float* __restrict__ sB,
               _Float16* __restrict__ pre)
{
    __shared__ float pA_s[256], pB_s[256];
    const int tid = threadIdx.x, lane = tid & 63, w = tid >> 6;
    const int arow = lane & 15, kb = lane >> 4;
    const int t0 = blockIdx.x * CH;

    COMPUTE_AB();

    // exclusive within-wave prefix (transform from wave start to lane's rows)
    float eA[4], eB[4];
    #pragma unroll
    for (int c = 0; c < 4; ++c) {
        eA[c] = __shfl_up(Ai[c], 16);
        eB[c] = __shfl_up(Bi[c], 16);
        if (kb == 0) { eA[c] = 1.f; eB[c] = 0.f; }
    }
    if (kb == 3) {   // wave totals
        #pragma unroll
        for (int c = 0; c < 4; ++c) {
            pA_s[w * 64 + c * 16 + arow] = Ai[c];
            pB_s[w * 64 + c * 16 + arow] = Bi[c];
        }
    }
    __syncthreads();

    // compose prior-wave totals: E = T_{w-1} o ... o T_0 (per column)
    float EA[4] = {1.f, 1.f, 1.f, 1.f}, EB[4] = {0.f, 0.f, 0.f, 0.f};
    for (int s2 = 0; s2 < w; ++s2) {
        #pragma unroll
        for (int c = 0; c < 4; ++c) {
            float qa = pA_s[s2 * 64 + c * 16 + arow];
            float qb = pB_s[s2 * 64 + c * 16 + arow];
            EB[c] = fmaf(qa, EB[c], qb);
            EA[c] *= qa;
        }
    }
    // per-row chunk-exclusive prefix; pack 4 rows' (PA,PB) into one 16B store
    _Float16* prebase = pre + (size_t)blockIdx.x * 8192;
    #pragma unroll
    for (int c = 0; c < 4; ++c) {
        float pa = eA[c] * EA[c];
        float pb = fmaf(eA[c], EB[c], eB[c]);
        f16x8 sv;
        #pragma unroll
        for (int reg = 0; reg < 4; ++reg) {
            sv[2 * reg]     = (_Float16)pa;
            sv[2 * reg + 1] = (_Float16)pb;
            if (t0 + w * 16 + kb * 4 + reg < NF - 1) {
                pb = fmaf(a[c][reg], pb, b[c][reg]);
                pa *= a[c][reg];
            }
        }
        *(f16x8*)&prebase[((((w * 4 + kb) * 4 + c) * 16 + arow) * 4) * 2] = sv;
    }
    // chunk summary -> sA,sB
    if (tid < 64) {
        float At = 1.f, Bt = 0.f;
        #pragma unroll
        for (int s2 = 0; s2 < 4; ++s2) {
            float qa = pA_s[s2 * 64 + tid], qb = pB_s[s2 * 64 + tid];
            Bt = fmaf(qa, Bt, qb);
            At *= qa;
        }
        sA[tid * NC + blockIdx.x] = At;
        sB[tid * NC + blockIdx.x] = Bt;
    }
}

// ---------------------------------------------------------------- K3
__global__ __launch_bounds__(256)
void k3_scan(const float* __restrict__ sA, const float* __restrict__ sB,
             float* __restrict__ u0)
{
    __shared__ float tA_s[4], tB_s[4];
    const int j    = blockIdx.x;
    const int lane = threadIdx.x & 63;
    const int w    = threadIdx.x >> 6;

    float PA[GPW], PB[GPW];
    float cA = 1.f, cB = 0.f;
    #pragma unroll
    for (int g = 0; g < GPW; ++g) {
        int c = (w * GPW + g) * 64 + lane;
        float A = 1.f, B = 0.f;
        if (c < NC) { A = sA[j * NC + c]; B = sB[j * NC + c]; }
        #pragma unroll
        for (int d = 1; d < 64; d <<= 1) {
            float pA = __shfl_up(A, d), pB = __shfl_up(B, d);
            if (lane >= d) { B = fmaf(A, pB, B); A *= pA; }
        }
        float eA = __shfl_up(A, 1), eB = __shfl_up(B, 1);
        if (lane == 0) { eA = 1.f; eB = 0.f; }
        PA[g] = eA * cA;
        PB[g] = fmaf(eA, cB, eB);
        float tA = __shfl(A, 63), tB = __shfl(B, 63);
        cB = fmaf(tA, cB, tB);
        cA *= tA;
    }
    if (lane == 0) { tA_s[w] = cA; tB_s[w] = cB; }
    __syncthreads();
    float uw = 0.f;
    for (int s2 = 0; s2 < w; ++s2) uw = fmaf(tA_s[s2], uw, tB_s[s2]);
    #pragma unroll
    for (int g = 0; g < GPW; ++g) {
        int c = (w * GPW + g) * 64 + lane;
        if (c < NC) u0[c * M + j] = fmaf(PA[g], uw, PB[g]);
    }
}

// ---------------------------------------------------------------- K4
// z[t][j] = PA*u0[chunk][j] + PB (16B/lane pre loads), then logits MFMA.
__global__ __launch_bounds__(256, 8)
void k4_light(const _Float16* __restrict__ pre, const float* __restrict__ u0,
              const _Float16* __restrict__ wlogpre, const float* __restrict__ bLog,
              float* __restrict__ out)
{
    __shared__ _Float16 z_s[64 * 72];
    const int tid = threadIdx.x, lane = tid & 63, w = tid >> 6;
    const int arow = lane & 15, kb = lane >> 4;
    const int t0 = blockIdx.x * CH;

    float u0v[4];
    #pragma unroll
    for (int c = 0; c < 4; ++c) u0v[c] = u0[blockIdx.x * 64 + c * 16 + arow];

    const _Float16* prebase = pre + (size_t)blockIdx.x * 8192;
    #pragma unroll
    for (int c = 0; c < 4; ++c) {
        f16x8 pv = *(const f16x8*)&prebase[((((w * 4 + kb) * 4 + c) * 16 + arow) * 4) * 2];
        #pragma unroll
        for (int reg = 0; reg < 4; ++reg) {
            int rl = w * 16 + kb * 4 + reg;
            float z = fmaf((float)pv[2 * reg], u0v[c], (float)pv[2 * reg + 1]);
            z_s[rl * 72 + c * 16 + arow] = (_Float16)z;
        }
    }
    __syncthreads();

    f32x4 acc2[4];
    #pragma unroll
    for (int ct = 0; ct < 4; ++ct) acc2[ct] = (f32x4){0.f, 0.f, 0.f, 0.f};
    #pragma unroll
    for (int ks = 0; ks < 2; ++ks) {
        f16x8 af = *(const f16x8*)&z_s[(w * 16 + arow) * 72 + ks * 32 + kb * 8];
        #pragma unroll
        for (int ct = 0; ct < 4; ++ct) {
            f16x8 bf = *(const f16x8*)&wlogpre[((ks * 4 + kb) * 64 + ct * 16 + arow) * 8];
            acc2[ct] = __builtin_amdgcn_mfma_f32_16x16x32_f16(af, bf, acc2[ct], 0, 0, 0);
        }
    }
    #pragma unroll
    for (int ct = 0; ct < 4; ++ct) {
        float bv = bLog[ct * 16 + arow];
        #pragma unroll
        for (int reg = 0; reg < 4; ++reg) {
            int t = t0 + w * 16 + kb * 4 + reg;
            if (t < NF) out[t * M + ct * 16 + arow] = acc2[ct][reg] + bv;
        }
    }
}

// ---------------------------------------------------------------- host
extern "C" void kernel_launch(void* const* d_in, const int* in_sizes, int n_in,
                              void* d_out, int out_size, void* d_ws, size_t ws_size,
                              hipStream_t stream)
{
    const float* X    = (const float*)d_in[0];
    const float* WL   = (const float*)d_in[2];
    const float* bL   = (const float*)d_in[3];
    const float* WR   = (const float*)d_in[4];
    const float* bR   = (const float*)d_in[5];
    const float* WLog = (const float*)d_in[6];
    const float* bLog = (const float*)d_in[7];

    // ws layout (~134 MB):
    _Float16* pre = (_Float16*)d_ws;                       // NC*8192 halfs (128 MB)
    float* sA = (float*)((char*)d_ws + (size_t)NC * 8192 * 2);
    float* sB = sA + (size_t)64 * NC;
    float* u0 = sB + (size_t)64 * NC;
    _Float16* wpre    = (_Float16*)(u0 + (size_t)64 * NC); // 16384 halfs
    _Float16* wlogpre = wpre + 16384;                      // 4096 halfs

    k0_pack<<<20, 256, 0, stream>>>(WL, WR, WLog, wpre, wlogpre);
    k1_prefix<<<NC, 256, 0, stream>>>(X, wpre, bL, bR, sA, sB, pre);
    k3_scan<<<M, 256, 0, stream>>>(sA, sB, u0);
    k4_light<<<NC, 256, 0, stream>>>(pre, u0, wlogpre, bLog, (float*)d_out);
}

// Round 9
// 208.939 us; speedup vs baseline: 17.8298x; 1.0300x over previous
//
#include <hip/hip_runtime.h>
#include <hip/hip_fp16.h>

// DeductronCTC v9 (3-kernel, prefix-store, LDS-staged X for full-line loads):
//   K0: pre-pack WL|WR and W_logit into MFMA fragment layout (f16) in ws.
//   K1: X staged f32->f16 via wave-private LDS (1KB-contiguous loads, full
//       cache lines -> no MSHR fragmentation), fp16 MFMA, sigmoid, a,b in
//       regs, per-row chunk-exclusive prefixes (PA,PB) packed f16, 16B/lane
//       stores + chunk summaries sA,sB.
//   K3: 2-level scan of chunk summaries -> u0 (chunk-start states).
//   K4: z = PA*u0 + PB (1 fma/elem), logits MFMA -> out. 16B/lane pre loads.
// Replay-safe: no buffer both read+written by a kernel, no aliasing.

constexpr int NF  = 500000;
constexpr int KIN = 128;
constexpr int M   = 64;
constexpr int CH  = 64;
constexpr int NC  = (NF + CH - 1) / CH;   // 7813
constexpr int NG  = (NC + 63) / 64;       // 123
constexpr int GPW = (NG + 3) / 4;         // 31

typedef _Float16 f16x8 __attribute__((ext_vector_type(8)));
typedef _Float16 f16x4 __attribute__((ext_vector_type(4)));
typedef float    f32x4 __attribute__((ext_vector_type(4)));

__device__ __forceinline__ float sig(float x) {
    // v_rcp_f32 (~1 ulp) instead of IEEE div sequence; error << f16 rounding
    return __builtin_amdgcn_rcpf(1.0f + __expf(-x));
}

// ---------------------------------------------------------------- K0
__global__ void k0_pack(const float* __restrict__ WL, const float* __restrict__ WR,
                        const float* __restrict__ WLog,
                        _Float16* __restrict__ wpre, _Float16* __restrict__ wlogpre)
{
    int flat = blockIdx.x * 1024 + threadIdx.x * 4;
    if (flat < 16384) {
        int k = flat >> 7, col = flat & 127;
        float4 v = (col < 64) ? *(const float4*)&WL[k * 64 + col]
                              : *(const float4*)&WR[k * 64 + (col - 64)];
        int kb = k >> 3, kj = k & 7;
        wpre[(kb * 128 + col + 0) * 8 + kj] = (_Float16)v.x;
        wpre[(kb * 128 + col + 1) * 8 + kj] = (_Float16)v.y;
        wpre[(kb * 128 + col + 2) * 8 + kj] = (_Float16)v.z;
        wpre[(kb * 128 + col + 3) * 8 + kj] = (_Float16)v.w;
    } else if (flat < 16384 + 4096) {
        int f2 = flat - 16384;
        int k = f2 >> 6, c = f2 & 63;
        float4 v = *(const float4*)&WLog[f2];
        int kb = k >> 3, kj = k & 7;
        wlogpre[(kb * 64 + c + 0) * 8 + kj] = (_Float16)v.x;
        wlogpre[(kb * 64 + c + 1) * 8 + kj] = (_Float16)v.y;
        wlogpre[(kb * 64 + c + 2) * 8 + kj] = (_Float16)v.z;
        wlogpre[(kb * 64 + c + 3) * 8 + kj] = (_Float16)v.w;
    }
}

// ---------------------------------------------------------------- K1
__global__ __launch_bounds__(256, 8)
void k1_prefix(const float* __restrict__ X, const _Float16* __restrict__ wpre,
               const float* __restrict__ bL, const float* __restrict__ bR,
               float* __restrict__ sA, float* __restrict__ sB,
               _Float16* __restrict__ pre)
{
    __shared__ _Float16 x_s[4][16][136];   // 17.4 KB, wave-private tiles
    __shared__ float pA_s[256], pB_s[256];
    const int tid = threadIdx.x, lane = tid & 63, w = tid >> 6;
    const int arow = lane & 15, kb = lane >> 4;
    const int t0 = blockIdx.x * CH;

    // ---- stage this wave's 16 X rows: 1KB-contiguous loads, f32->f16
    // (wave-private tile: same-wave DS ordering, no barrier needed)
    const int r0 = t0 + w * 16;
    #pragma unroll
    for (int it = 0; it < 8; ++it) {
        int flat = it * 256 + lane * 4;           // 16*128 floats
        int r = flat >> 7, k = flat & 127;
        float4 v = make_float4(0.f, 0.f, 0.f, 0.f);
        if (r0 + r < NF) v = *(const float4*)&X[(size_t)(r0 + r) * KIN + k];
        f16x4 h = { (_Float16)v.x, (_Float16)v.y, (_Float16)v.z, (_Float16)v.w };
        *(f16x4*)&x_s[w][r][k] = h;
    }

    // ---- MFMA: wave w -> rows [w*16, +16) x 128 cols
    f32x4 acc[8];
    #pragma unroll
    for (int c = 0; c < 8; ++c) acc[c] = (f32x4){0.f, 0.f, 0.f, 0.f};
    #pragma unroll
    for (int s = 0; s < 4; ++s) {
        f16x8 af = *(const f16x8*)&x_s[w][arow][s * 32 + kb * 8];
        #pragma unroll
        for (int c = 0; c < 8; ++c) {
            f16x8 bf = *(const f16x8*)&wpre[((s * 4 + kb) * 128 + c * 16 + arow) * 8];
            acc[c] = __builtin_amdgcn_mfma_f32_16x16x32_f16(af, bf, acc[c], 0, 0, 0);
        }
    }

    // ---- sigmoid epilogue: a,b in registers
    float a[4][4], b[4][4];
    #pragma unroll
    for (int c = 0; c < 4; ++c) {
        float blv = bL[c * 16 + arow], brv = bR[c * 16 + arow];
        #pragma unroll
        for (int reg = 0; reg < 4; ++reg) {
            float lv = sig(acc[c][reg] + blv);
            float rv = sig(acc[c + 4][reg] + brv);
            a[c][reg] = lv * rv;
            b[c][reg] = 1.0f - lv;
        }
    }

    // ---- local 4-row compose + 2-step kb-group shfl scan (inclusive)
    float Ai[4], Bi[4];
    #pragma unroll
    for (int c = 0; c < 4; ++c) {
        float A = 1.f, B = 0.f;
        #pragma unroll
        for (int reg = 0; reg < 4; ++reg) {
            if (t0 + w * 16 + kb * 4 + reg < NF - 1) {
                B = fmaf(a[c][reg], B, b[c][reg]);
                A *= a[c][reg];
            }
        }
        Ai[c] = A; Bi[c] = B;
    }
    #pragma unroll
    for (int d = 16; d < 64; d <<= 1) {
        #pragma unroll
        for (int c = 0; c < 4; ++c) {
            float pA = __shfl_up(Ai[c], d), pB = __shfl_up(Bi[c], d);
            if (lane >= d) { Bi[c] = fmaf(Ai[c], pB, Bi[c]); Ai[c] *= pA; }
        }
    }

    // exclusive within-wave prefix (transform from wave start to lane's rows)
    float eA[4], eB[4];
    #pragma unroll
    for (int c = 0; c < 4; ++c) {
        eA[c] = __shfl_up(Ai[c], 16);
        eB[c] = __shfl_up(Bi[c], 16);
        if (kb == 0) { eA[c] = 1.f; eB[c] = 0.f; }
    }
    if (kb == 3) {   // wave totals
        #pragma unroll
        for (int c = 0; c < 4; ++c) {
            pA_s[w * 64 + c * 16 + arow] = Ai[c];
            pB_s[w * 64 + c * 16 + arow] = Bi[c];
        }
    }
    __syncthreads();

    // compose prior-wave totals: E = T_{w-1} o ... o T_0 (per column)
    float EA[4] = {1.f, 1.f, 1.f, 1.f}, EB[4] = {0.f, 0.f, 0.f, 0.f};
    for (int s2 = 0; s2 < w; ++s2) {
        #pragma unroll
        for (int c = 0; c < 4; ++c) {
            float qa = pA_s[s2 * 64 + c * 16 + arow];
            float qb = pB_s[s2 * 64 + c * 16 + arow];
            EB[c] = fmaf(qa, EB[c], qb);
            EA[c] *= qa;
        }
    }
    // per-row chunk-exclusive prefix; pack 4 rows' (PA,PB) into one 16B store
    _Float16* prebase = pre + (size_t)blockIdx.x * 8192;
    #pragma unroll
    for (int c = 0; c < 4; ++c) {
        float pa = eA[c] * EA[c];
        float pb = fmaf(eA[c], EB[c], eB[c]);
        f16x8 sv;
        #pragma unroll
        for (int reg = 0; reg < 4; ++reg) {
            sv[2 * reg]     = (_Float16)pa;
            sv[2 * reg + 1] = (_Float16)pb;
            if (t0 + w * 16 + kb * 4 + reg < NF - 1) {
                pb = fmaf(a[c][reg], pb, b[c][reg]);
                pa *= a[c][reg];
            }
        }
        *(f16x8*)&prebase[((((w * 4 + kb) * 4 + c) * 16 + arow) * 4) * 2] = sv;
    }
    // chunk summary -> sA,sB
    if (tid < 64) {
        float At = 1.f, Bt = 0.f;
        #pragma unroll
        for (int s2 = 0; s2 < 4; ++s2) {
            float qa = pA_s[s2 * 64 + tid], qb = pB_s[s2 * 64 + tid];
            Bt = fmaf(qa, Bt, qb);
            At *= qa;
        }
        sA[tid * NC + blockIdx.x] = At;
        sB[tid * NC + blockIdx.x] = Bt;
    }
}

// ---------------------------------------------------------------- K3
__global__ __launch_bounds__(256)
void k3_scan(const float* __restrict__ sA, const float* __restrict__ sB,
             float* __restrict__ u0)
{
    __shared__ float tA_s[4], tB_s[4];
    const int j    = blockIdx.x;
    const int lane = threadIdx.x & 63;
    const int w    = threadIdx.x >> 6;

    float PA[GPW], PB[GPW];
    float cA = 1.f, cB = 0.f;
    #pragma unroll
    for (int g = 0; g < GPW; ++g) {
        int c = (w * GPW + g) * 64 + lane;
        float A = 1.f, B = 0.f;
        if (c < NC) { A = sA[j * NC + c]; B = sB[j * NC + c]; }
        #pragma unroll
        for (int d = 1; d < 64; d <<= 1) {
            float pA = __shfl_up(A, d), pB = __shfl_up(B, d);
            if (lane >= d) { B = fmaf(A, pB, B); A *= pA; }
        }
        float eA = __shfl_up(A, 1), eB = __shfl_up(B, 1);
        if (lane == 0) { eA = 1.f; eB = 0.f; }
        PA[g] = eA * cA;
        PB[g] = fmaf(eA, cB, eB);
        float tA = __shfl(A, 63), tB = __shfl(B, 63);
        cB = fmaf(tA, cB, tB);
        cA *= tA;
    }
    if (lane == 0) { tA_s[w] = cA; tB_s[w] = cB; }
    __syncthreads();
    float uw = 0.f;
    for (int s2 = 0; s2 < w; ++s2) uw = fmaf(tA_s[s2], uw, tB_s[s2]);
    #pragma unroll
    for (int g = 0; g < GPW; ++g) {
        int c = (w * GPW + g) * 64 + lane;
        if (c < NC) u0[c * M + j] = fmaf(PA[g], uw, PB[g]);
    }
}

// ---------------------------------------------------------------- K4
// z[t][j] = PA*u0[chunk][j] + PB (16B/lane pre loads), then logits MFMA.
__global__ __launch_bounds__(256, 8)
void k4_light(const _Float16* __restrict__ pre, const float* __restrict__ u0,
              const _Float16* __restrict__ wlogpre, const float* __restrict__ bLog,
              float* __restrict__ out)
{
    __shared__ _Float16 z_s[64 * 72];
    const int tid = threadIdx.x, lane = tid & 63, w = tid >> 6;
    const int arow = lane & 15, kb = lane >> 4;
    const int t0 = blockIdx.x * CH;

    float u0v[4];
    #pragma unroll
    for (int c = 0; c < 4; ++c) u0v[c] = u0[blockIdx.x * 64 + c * 16 + arow];

    const _Float16* prebase = pre + (size_t)blockIdx.x * 8192;
    #pragma unroll
    for (int c = 0; c < 4; ++c) {
        f16x8 pv = *(const f16x8*)&prebase[((((w * 4 + kb) * 4 + c) * 16 + arow) * 4) * 2];
        #pragma unroll
        for (int reg = 0; reg < 4; ++reg) {
            int rl = w * 16 + kb * 4 + reg;
            float z = fmaf((float)pv[2 * reg], u0v[c], (float)pv[2 * reg + 1]);
            z_s[rl * 72 + c * 16 + arow] = (_Float16)z;
        }
    }
    __syncthreads();

    f32x4 acc2[4];
    #pragma unroll
    for (int ct = 0; ct < 4; ++ct) acc2[ct] = (f32x4){0.f, 0.f, 0.f, 0.f};
    #pragma unroll
    for (int ks = 0; ks < 2; ++ks) {
        f16x8 af = *(const f16x8*)&z_s[(w * 16 + arow) * 72 + ks * 32 + kb * 8];
        #pragma unroll
        for (int ct = 0; ct < 4; ++ct) {
            f16x8 bf = *(const f16x8*)&wlogpre[((ks * 4 + kb) * 64 + ct * 16 + arow) * 8];
            acc2[ct] = __builtin_amdgcn_mfma_f32_16x16x32_f16(af, bf, acc2[ct], 0, 0, 0);
        }
    }
    #pragma unroll
    for (int ct = 0; ct < 4; ++ct) {
        float bv = bLog[ct * 16 + arow];
        #pragma unroll
        for (int reg = 0; reg < 4; ++reg) {
            int t = t0 + w * 16 + kb * 4 + reg;
            if (t < NF) out[t * M + ct * 16 + arow] = acc2[ct][reg] + bv;
        }
    }
}

// ---------------------------------------------------------------- host
extern "C" void kernel_launch(void* const* d_in, const int* in_sizes, int n_in,
                              void* d_out, int out_size, void* d_ws, size_t ws_size,
                              hipStream_t stream)
{
    const float* X    = (const float*)d_in[0];
    const float* WL   = (const float*)d_in[2];
    const float* bL   = (const float*)d_in[3];
    const float* WR   = (const float*)d_in[4];
    const float* bR   = (const float*)d_in[5];
    const float* WLog = (const float*)d_in[6];
    const float* bLog = (const float*)d_in[7];

    // ws layout (~134 MB):
    _Float16* pre = (_Float16*)d_ws;                       // NC*8192 halfs (128 MB)
    float* sA = (float*)((char*)d_ws + (size_t)NC * 8192 * 2);
    float* sB = sA + (size_t)64 * NC;
    float* u0 = sB + (size_t)64 * NC;
    _Float16* wpre    = (_Float16*)(u0 + (size_t)64 * NC); // 16384 halfs
    _Float16* wlogpre = wpre + 16384;                      // 4096 halfs

    k0_pack<<<20, 256, 0, stream>>>(WL, WR, WLog, wpre, wlogpre);
    k1_prefix<<<NC, 256, 0, stream>>>(X, wpre, bL, bR, sA, sB, pre);
    k3_scan<<<M, 256, 0, stream>>>(sA, sB, u0);
    k4_light<<<NC, 256, 0, stream>>>(pre, u0, wlogpre, bLog, (float*)d_out);
}

// Round 11
// 164.332 us; speedup vs baseline: 22.6697x; 1.2714x over previous
//
#include <hip/hip_runtime.h>
#include <hip/hip_fp16.h>

// DeductronCTC v10b (v10 with cvt_pkrtz type fix):
//   K0: pre-pack WL|WR and W_logit into MFMA fragment layout (f16) in ws.
//   K1: W staged LDS (once per block, conflict-free b128), X direct-to-reg
//       with packed cvt, fp16 MFMA, sigmoid, a,b in regs, per-row chunk-
//       exclusive prefixes (PA,PB) f16-packed, 16B/lane stores + summaries.
//   K3: 2-level scan of chunk summaries -> u0 (chunk-start states).
//   K4: z = PA*u0 + PB, logits MFMA, nontemporal out stores.
// Replay-safe: no buffer both read+written by a kernel, no aliasing.

constexpr int NF  = 500000;
constexpr int KIN = 128;
constexpr int M   = 64;
constexpr int CH  = 64;
constexpr int NC  = (NF + CH - 1) / CH;   // 7813
constexpr int NG  = (NC + 63) / 64;       // 123
constexpr int GPW = (NG + 3) / 4;         // 31

typedef _Float16 f16x8 __attribute__((ext_vector_type(8)));
typedef __fp16   fp16x2 __attribute__((ext_vector_type(2)));  // cvt_pkrtz return type
typedef float    f32x4 __attribute__((ext_vector_type(4)));

__device__ __forceinline__ float sig(float x) {
    return __builtin_amdgcn_rcpf(1.0f + __expf(-x));
}

// ---------------------------------------------------------------- K0
__global__ void k0_pack(const float* __restrict__ WL, const float* __restrict__ WR,
                        const float* __restrict__ WLog,
                        _Float16* __restrict__ wpre, _Float16* __restrict__ wlogpre)
{
    int flat = blockIdx.x * 1024 + threadIdx.x * 4;
    if (flat < 16384) {
        int k = flat >> 7, col = flat & 127;
        float4 v = (col < 64) ? *(const float4*)&WL[k * 64 + col]
                              : *(const float4*)&WR[k * 64 + (col - 64)];
        int kb = k >> 3, kj = k & 7;
        wpre[(kb * 128 + col + 0) * 8 + kj] = (_Float16)v.x;
        wpre[(kb * 128 + col + 1) * 8 + kj] = (_Float16)v.y;
        wpre[(kb * 128 + col + 2) * 8 + kj] = (_Float16)v.z;
        wpre[(kb * 128 + col + 3) * 8 + kj] = (_Float16)v.w;
    } else if (flat < 16384 + 4096) {
        int f2 = flat - 16384;
        int k = f2 >> 6, c = f2 & 63;
        float4 v = *(const float4*)&WLog[f2];
        int kb = k >> 3, kj = k & 7;
        wlogpre[(kb * 64 + c + 0) * 8 + kj] = (_Float16)v.x;
        wlogpre[(kb * 64 + c + 1) * 8 + kj] = (_Float16)v.y;
        wlogpre[(kb * 64 + c + 2) * 8 + kj] = (_Float16)v.z;
        wlogpre[(kb * 64 + c + 3) * 8 + kj] = (_Float16)v.w;
    }
}

// ---------------------------------------------------------------- K1
__global__ __launch_bounds__(256, 4)
void k1_prefix(const float* __restrict__ X, const _Float16* __restrict__ wpre,
               const float* __restrict__ bL, const float* __restrict__ bR,
               float* __restrict__ sA, float* __restrict__ sB,
               _Float16* __restrict__ pre)
{
    __shared__ _Float16 w_s[16384];          // 32 KB: B-frags, block-shared
    __shared__ float pA_s[256], pB_s[256];
    const int tid = threadIdx.x, lane = tid & 63, w = tid >> 6;
    const int arow = lane & 15, kb = lane >> 4;
    const int t0 = blockIdx.x * CH;

    // stage prepacked W: contiguous 16B copies, conflict-free
    #pragma unroll
    for (int i = 0; i < 8; ++i) {
        int c16 = i * 256 + tid;
        *(f16x8*)&w_s[c16 * 8] = ((const f16x8*)wpre)[c16];
    }
    __syncthreads();

    // ---- MFMA: A-frags direct from global X (packed cvt), B from LDS
    f32x4 acc[8];
    #pragma unroll
    for (int c = 0; c < 8; ++c) acc[c] = (f32x4){0.f, 0.f, 0.f, 0.f};
    {
        const int xrow = t0 + w * 16 + arow;
        const float* xp = X + (size_t)xrow * KIN;
        const bool rowok = xrow < NF;
        #pragma unroll
        for (int s = 0; s < 4; ++s) {
            f32x4 v0 = (f32x4){0.f, 0.f, 0.f, 0.f}, v1 = v0;
            if (rowok) {
                v0 = *(const f32x4*)&xp[s * 32 + kb * 8];
                v1 = *(const f32x4*)&xp[s * 32 + kb * 8 + 4];
            }
            fp16x2 p0 = __builtin_amdgcn_cvt_pkrtz(v0.x, v0.y);
            fp16x2 p1 = __builtin_amdgcn_cvt_pkrtz(v0.z, v0.w);
            fp16x2 p2 = __builtin_amdgcn_cvt_pkrtz(v1.x, v1.y);
            fp16x2 p3 = __builtin_amdgcn_cvt_pkrtz(v1.z, v1.w);
            f16x8 af = { (_Float16)p0[0], (_Float16)p0[1],
                         (_Float16)p1[0], (_Float16)p1[1],
                         (_Float16)p2[0], (_Float16)p2[1],
                         (_Float16)p3[0], (_Float16)p3[1] };
            #pragma unroll
            for (int c = 0; c < 8; ++c) {
                f16x8 bf = *(const f16x8*)&w_s[((s * 4 + kb) * 128 + c * 16 + arow) * 8];
                acc[c] = __builtin_amdgcn_mfma_f32_16x16x32_f16(af, bf, acc[c], 0, 0, 0);
            }
        }
    }

    // ---- sigmoid epilogue: a,b in registers
    float a[4][4], b[4][4];
    #pragma unroll
    for (int c = 0; c < 4; ++c) {
        float blv = bL[c * 16 + arow], brv = bR[c * 16 + arow];
        #pragma unroll
        for (int reg = 0; reg < 4; ++reg) {
            float lv = sig(acc[c][reg] + blv);
            float rv = sig(acc[c + 4][reg] + brv);
            a[c][reg] = lv * rv;
            b[c][reg] = 1.0f - lv;
        }
    }

    // ---- local 4-row compose + 2-step kb-group shfl scan (inclusive)
    float Ai[4], Bi[4];
    #pragma unroll
    for (int c = 0; c < 4; ++c) {
        float A = 1.f, B = 0.f;
        #pragma unroll
        for (int reg = 0; reg < 4; ++reg) {
            if (t0 + w * 16 + kb * 4 + reg < NF - 1) {
                B = fmaf(a[c][reg], B, b[c][reg]);
                A *= a[c][reg];
            }
        }
        Ai[c] = A; Bi[c] = B;
    }
    #pragma unroll
    for (int d = 16; d < 64; d <<= 1) {
        #pragma unroll
        for (int c = 0; c < 4; ++c) {
            float pA = __shfl_up(Ai[c], d), pB = __shfl_up(Bi[c], d);
            if (lane >= d) { Bi[c] = fmaf(Ai[c], pB, Bi[c]); Ai[c] *= pA; }
        }
    }

    // exclusive within-wave prefix
    float eA[4], eB[4];
    #pragma unroll
    for (int c = 0; c < 4; ++c) {
        eA[c] = __shfl_up(Ai[c], 16);
        eB[c] = __shfl_up(Bi[c], 16);
        if (kb == 0) { eA[c] = 1.f; eB[c] = 0.f; }
    }
    if (kb == 3) {   // wave totals
        #pragma unroll
        for (int c = 0; c < 4; ++c) {
            pA_s[w * 64 + c * 16 + arow] = Ai[c];
            pB_s[w * 64 + c * 16 + arow] = Bi[c];
        }
    }
    __syncthreads();

    // compose prior-wave totals
    float EA[4] = {1.f, 1.f, 1.f, 1.f}, EB[4] = {0.f, 0.f, 0.f, 0.f};
    for (int s2 = 0; s2 < w; ++s2) {
        #pragma unroll
        for (int c = 0; c < 4; ++c) {
            float qa = pA_s[s2 * 64 + c * 16 + arow];
            float qb = pB_s[s2 * 64 + c * 16 + arow];
            EB[c] = fmaf(qa, EB[c], qb);
            EA[c] *= qa;
        }
    }
    // per-row chunk-exclusive prefix; pack 4 rows' (PA,PB) into one 16B store
    _Float16* prebase = pre + (size_t)blockIdx.x * 8192;
    #pragma unroll
    for (int c = 0; c < 4; ++c) {
        float pa = eA[c] * EA[c];
        float pb = fmaf(eA[c], EB[c], eB[c]);
        f16x8 sv;
        #pragma unroll
        for (int reg = 0; reg < 4; ++reg) {
            fp16x2 pp = __builtin_amdgcn_cvt_pkrtz(pa, pb);
            sv[2 * reg]     = (_Float16)pp[0];
            sv[2 * reg + 1] = (_Float16)pp[1];
            if (t0 + w * 16 + kb * 4 + reg < NF - 1) {
                pb = fmaf(a[c][reg], pb, b[c][reg]);
                pa *= a[c][reg];
            }
        }
        *(f16x8*)&prebase[((((w * 4 + kb) * 4 + c) * 16 + arow) * 4) * 2] = sv;
    }
    // chunk summary -> sA,sB
    if (tid < 64) {
        float At = 1.f, Bt = 0.f;
        #pragma unroll
        for (int s2 = 0; s2 < 4; ++s2) {
            float qa = pA_s[s2 * 64 + tid], qb = pB_s[s2 * 64 + tid];
            Bt = fmaf(qa, Bt, qb);
            At *= qa;
        }
        sA[tid * NC + blockIdx.x] = At;
        sB[tid * NC + blockIdx.x] = Bt;
    }
}

// ---------------------------------------------------------------- K3
__global__ __launch_bounds__(256)
void k3_scan(const float* __restrict__ sA, const float* __restrict__ sB,
             float* __restrict__ u0)
{
    __shared__ float tA_s[4], tB_s[4];
    const int j    = blockIdx.x;
    const int lane = threadIdx.x & 63;
    const int w    = threadIdx.x >> 6;

    float PA[GPW], PB[GPW];
    float cA = 1.f, cB = 0.f;
    #pragma unroll
    for (int g = 0; g < GPW; ++g) {
        int c = (w * GPW + g) * 64 + lane;
        float A = 1.f, B = 0.f;
        if (c < NC) { A = sA[j * NC + c]; B = sB[j * NC + c]; }
        #pragma unroll
        for (int d = 1; d < 64; d <<= 1) {
            float pA = __shfl_up(A, d), pB = __shfl_up(B, d);
            if (lane >= d) { B = fmaf(A, pB, B); A *= pA; }
        }
        float eA = __shfl_up(A, 1), eB = __shfl_up(B, 1);
        if (lane == 0) { eA = 1.f; eB = 0.f; }
        PA[g] = eA * cA;
        PB[g] = fmaf(eA, cB, eB);
        float tA = __shfl(A, 63), tB = __shfl(B, 63);
        cB = fmaf(tA, cB, tB);
        cA *= tA;
    }
    if (lane == 0) { tA_s[w] = cA; tB_s[w] = cB; }
    __syncthreads();
    float uw = 0.f;
    for (int s2 = 0; s2 < w; ++s2) uw = fmaf(tA_s[s2], uw, tB_s[s2]);
    #pragma unroll
    for (int g = 0; g < GPW; ++g) {
        int c = (w * GPW + g) * 64 + lane;
        if (c < NC) u0[c * M + j] = fmaf(PA[g], uw, PB[g]);
    }
}

// ---------------------------------------------------------------- K4
__global__ __launch_bounds__(256, 8)
void k4_light(const _Float16* __restrict__ pre, const float* __restrict__ u0,
              const _Float16* __restrict__ wlogpre, const float* __restrict__ bLog,
              float* __restrict__ out)
{
    __shared__ _Float16 z_s[64 * 72];
    const int tid = threadIdx.x, lane = tid & 63, w = tid >> 6;
    const int arow = lane & 15, kb = lane >> 4;
    const int t0 = blockIdx.x * CH;

    float u0v[4];
    #pragma unroll
    for (int c = 0; c < 4; ++c) u0v[c] = u0[blockIdx.x * 64 + c * 16 + arow];

    const _Float16* prebase = pre + (size_t)blockIdx.x * 8192;
    #pragma unroll
    for (int c = 0; c < 4; ++c) {
        f16x8 pv = *(const f16x8*)&prebase[((((w * 4 + kb) * 4 + c) * 16 + arow) * 4) * 2];
        #pragma unroll
        for (int reg = 0; reg < 4; ++reg) {
            int rl = w * 16 + kb * 4 + reg;
            float z = fmaf((float)pv[2 * reg], u0v[c], (float)pv[2 * reg + 1]);
            z_s[rl * 72 + c * 16 + arow] = (_Float16)z;
        }
    }
    __syncthreads();

    f32x4 acc2[4];
    #pragma unroll
    for (int ct = 0; ct < 4; ++ct) acc2[ct] = (f32x4){0.f, 0.f, 0.f, 0.f};
    #pragma unroll
    for (int ks = 0; ks < 2; ++ks) {
        f16x8 af = *(const f16x8*)&z_s[(w * 16 + arow) * 72 + ks * 32 + kb * 8];
        #pragma unroll
        for (int ct = 0; ct < 4; ++ct) {
            f16x8 bf = *(const f16x8*)&wlogpre[((ks * 4 + kb) * 64 + ct * 16 + arow) * 8];
            acc2[ct] = __builtin_amdgcn_mfma_f32_16x16x32_f16(af, bf, acc2[ct], 0, 0, 0);
        }
    }
    #pragma unroll
    for (int ct = 0; ct < 4; ++ct) {
        float bv = bLog[ct * 16 + arow];
        #pragma unroll
        for (int reg = 0; reg < 4; ++reg) {
            int t = t0 + w * 16 + kb * 4 + reg;
            if (t < NF)
                __builtin_nontemporal_store(acc2[ct][reg] + bv,
                                            &out[t * M + ct * 16 + arow]);
        }
    }
}

// ---------------------------------------------------------------- host
extern "C" void kernel_launch(void* const* d_in, const int* in_sizes, int n_in,
                              void* d_out, int out_size, void* d_ws, size_t ws_size,
                              hipStream_t stream)
{
    const float* X    = (const float*)d_in[0];
    const float* WL   = (const float*)d_in[2];
    const float* bL   = (const float*)d_in[3];
    const float* WR   = (const float*)d_in[4];
    const float* bR   = (const float*)d_in[5];
    const float* WLog = (const float*)d_in[6];
    const float* bLog = (const float*)d_in[7];

    // ws layout (~134 MB):
    _Float16* pre = (_Float16*)d_ws;                       // NC*8192 halfs (128 MB)
    float* sA = (float*)((char*)d_ws + (size_t)NC * 8192 * 2);
    float* sB = sA + (size_t)64 * NC;
    float* u0 = sB + (size_t)64 * NC;
    _Float16* wpre    = (_Float16*)(u0 + (size_t)64 * NC); // 16384 halfs
    _Float16* wlogpre = wpre + 16384;                      // 4096 halfs

    k0_pack<<<20, 256, 0, stream>>>(WL, WR, WLog, wpre, wlogpre);
    k1_prefix<<<NC, 256, 0, stream>>>(X, wpre, bL, bR, sA, sB, pre);
    k3_scan<<<M, 256, 0, stream>>>(sA, sB, u0);
    k4_light<<<NC, 256, 0, stream>>>(pre, u0, wlogpre, bLog, (float*)d_out);
}

// Round 12
// 159.434 us; speedup vs baseline: 23.3661x; 1.0307x over previous
//
#include <hip/hip_runtime.h>
#include <hip/hip_fp16.h>

// DeductronCTC v11 (persistent K1 + register-pipelined X):
//   K0: pre-pack WL|WR and W_logit into MFMA fragment layout (f16) in ws.
//   K1: PERSISTENT grid (1024 blocks); W staged to LDS once per block;
//       grid-stride over chunks with next-chunk X prefetched into registers
//       during the scan/emit epilogue. Emits per-row chunk-exclusive prefix
//       transforms (PA,PB) f16-packed (16B/lane) + chunk summaries.
//   K3: 2-level scan of chunk summaries -> u0 (chunk-start states).
//   K4: z = PA*u0 + PB, logits MFMA, nontemporal pre loads + out stores.
// Replay-safe: no buffer both read+written by a kernel, no aliasing.

constexpr int NF  = 500000;
constexpr int KIN = 128;
constexpr int M   = 64;
constexpr int CH  = 64;
constexpr int NC  = (NF + CH - 1) / CH;   // 7813
constexpr int NG  = (NC + 63) / 64;       // 123
constexpr int GPW = (NG + 3) / 4;         // 31
constexpr int K1GRID = 1024;              // 4 blocks/CU * 256 CU

typedef _Float16 f16x8 __attribute__((ext_vector_type(8)));
typedef __fp16   fp16x2 __attribute__((ext_vector_type(2)));
typedef float    f32x4 __attribute__((ext_vector_type(4)));

__device__ __forceinline__ float sig(float x) {
    return __builtin_amdgcn_rcpf(1.0f + __expf(-x));
}

// ---------------------------------------------------------------- K0
__global__ void k0_pack(const float* __restrict__ WL, const float* __restrict__ WR,
                        const float* __restrict__ WLog,
                        _Float16* __restrict__ wpre, _Float16* __restrict__ wlogpre)
{
    int flat = blockIdx.x * 1024 + threadIdx.x * 4;
    if (flat < 16384) {
        int k = flat >> 7, col = flat & 127;
        float4 v = (col < 64) ? *(const float4*)&WL[k * 64 + col]
                              : *(const float4*)&WR[k * 64 + (col - 64)];
        int kb = k >> 3, kj = k & 7;
        wpre[(kb * 128 + col + 0) * 8 + kj] = (_Float16)v.x;
        wpre[(kb * 128 + col + 1) * 8 + kj] = (_Float16)v.y;
        wpre[(kb * 128 + col + 2) * 8 + kj] = (_Float16)v.z;
        wpre[(kb * 128 + col + 3) * 8 + kj] = (_Float16)v.w;
    } else if (flat < 16384 + 4096) {
        int f2 = flat - 16384;
        int k = f2 >> 6, c = f2 & 63;
        float4 v = *(const float4*)&WLog[f2];
        int kb = k >> 3, kj = k & 7;
        wlogpre[(kb * 64 + c + 0) * 8 + kj] = (_Float16)v.x;
        wlogpre[(kb * 64 + c + 1) * 8 + kj] = (_Float16)v.y;
        wlogpre[(kb * 64 + c + 2) * 8 + kj] = (_Float16)v.z;
        wlogpre[(kb * 64 + c + 3) * 8 + kj] = (_Float16)v.w;
    }
}

// ---------------------------------------------------------------- K1
__global__ __launch_bounds__(256, 4)
void k1_prefix(const float* __restrict__ X, const _Float16* __restrict__ wpre,
               const float* __restrict__ bL, const float* __restrict__ bR,
               float* __restrict__ sA, float* __restrict__ sB,
               _Float16* __restrict__ pre)
{
    __shared__ _Float16 w_s[16384];          // 32 KB B-frags, staged ONCE
    __shared__ float pA_s[256], pB_s[256];
    const int tid = threadIdx.x, lane = tid & 63, w = tid >> 6;
    const int arow = lane & 15, kb = lane >> 4;

    #pragma unroll
    for (int i = 0; i < 8; ++i) {
        int c16 = i * 256 + tid;
        *(f16x8*)&w_s[c16 * 8] = ((const f16x8*)wpre)[c16];
    }
    __syncthreads();

    float blv[4], brv[4];
    #pragma unroll
    for (int c = 0; c < 4; ++c) { blv[c] = bL[c * 16 + arow]; brv[c] = bR[c * 16 + arow]; }

    // prologue: load first chunk's X rows (8 x f32x4 per thread)
    f32x4 xv[8];
    int cid = blockIdx.x;
    {
        const int xrow = cid * CH + w * 16 + arow;
        const float* xp = X + (size_t)xrow * KIN;
        const bool rowok = xrow < NF;
        #pragma unroll
        for (int s = 0; s < 4; ++s) {
            xv[2 * s]     = rowok ? *(const f32x4*)&xp[s * 32 + kb * 8]
                                  : (f32x4){0.f, 0.f, 0.f, 0.f};
            xv[2 * s + 1] = rowok ? *(const f32x4*)&xp[s * 32 + kb * 8 + 4]
                                  : (f32x4){0.f, 0.f, 0.f, 0.f};
        }
    }

    while (cid < NC) {
        const int t0 = cid * CH;
        const int nxt = cid + K1GRID;

        // ---- MFMA on current xv
        f32x4 acc[8];
        #pragma unroll
        for (int c = 0; c < 8; ++c) acc[c] = (f32x4){0.f, 0.f, 0.f, 0.f};
        #pragma unroll
        for (int s = 0; s < 4; ++s) {
            fp16x2 p0 = __builtin_amdgcn_cvt_pkrtz(xv[2 * s].x, xv[2 * s].y);
            fp16x2 p1 = __builtin_amdgcn_cvt_pkrtz(xv[2 * s].z, xv[2 * s].w);
            fp16x2 p2 = __builtin_amdgcn_cvt_pkrtz(xv[2 * s + 1].x, xv[2 * s + 1].y);
            fp16x2 p3 = __builtin_amdgcn_cvt_pkrtz(xv[2 * s + 1].z, xv[2 * s + 1].w);
            f16x8 af = { (_Float16)p0[0], (_Float16)p0[1],
                         (_Float16)p1[0], (_Float16)p1[1],
                         (_Float16)p2[0], (_Float16)p2[1],
                         (_Float16)p3[0], (_Float16)p3[1] };
            #pragma unroll
            for (int c = 0; c < 8; ++c) {
                f16x8 bf = *(const f16x8*)&w_s[((s * 4 + kb) * 128 + c * 16 + arow) * 8];
                acc[c] = __builtin_amdgcn_mfma_f32_16x16x32_f16(af, bf, acc[c], 0, 0, 0);
            }
        }

        // ---- prefetch next chunk's X (latency hidden by epilogue below)
        if (nxt < NC) {
            const int xrow = nxt * CH + w * 16 + arow;
            const float* xp = X + (size_t)xrow * KIN;
            const bool rowok = xrow < NF;
            #pragma unroll
            for (int s = 0; s < 4; ++s) {
                xv[2 * s]     = rowok ? *(const f32x4*)&xp[s * 32 + kb * 8]
                                      : (f32x4){0.f, 0.f, 0.f, 0.f};
                xv[2 * s + 1] = rowok ? *(const f32x4*)&xp[s * 32 + kb * 8 + 4]
                                      : (f32x4){0.f, 0.f, 0.f, 0.f};
            }
        }

        // ---- sigmoid epilogue: a,b in registers
        float a[4][4], b[4][4];
        #pragma unroll
        for (int c = 0; c < 4; ++c) {
            #pragma unroll
            for (int reg = 0; reg < 4; ++reg) {
                float lv = sig(acc[c][reg] + blv[c]);
                float rv = sig(acc[c + 4][reg] + brv[c]);
                a[c][reg] = lv * rv;
                b[c][reg] = 1.0f - lv;
            }
        }

        // ---- local 4-row compose + 2-step kb-group shfl scan (inclusive)
        float Ai[4], Bi[4];
        #pragma unroll
        for (int c = 0; c < 4; ++c) {
            float A = 1.f, B = 0.f;
            #pragma unroll
            for (int reg = 0; reg < 4; ++reg) {
                if (t0 + w * 16 + kb * 4 + reg < NF - 1) {
                    B = fmaf(a[c][reg], B, b[c][reg]);
                    A *= a[c][reg];
                }
            }
            Ai[c] = A; Bi[c] = B;
        }
        #pragma unroll
        for (int d = 16; d < 64; d <<= 1) {
            #pragma unroll
            for (int c = 0; c < 4; ++c) {
                float pA = __shfl_up(Ai[c], d), pB = __shfl_up(Bi[c], d);
                if (lane >= d) { Bi[c] = fmaf(Ai[c], pB, Bi[c]); Ai[c] *= pA; }
            }
        }

        // exclusive within-wave prefix
        float eA[4], eB[4];
        #pragma unroll
        for (int c = 0; c < 4; ++c) {
            eA[c] = __shfl_up(Ai[c], 16);
            eB[c] = __shfl_up(Bi[c], 16);
            if (kb == 0) { eA[c] = 1.f; eB[c] = 0.f; }
        }
        if (kb == 3) {   // wave totals
            #pragma unroll
            for (int c = 0; c < 4; ++c) {
                pA_s[w * 64 + c * 16 + arow] = Ai[c];
                pB_s[w * 64 + c * 16 + arow] = Bi[c];
            }
        }
        __syncthreads();

        // compose prior-wave totals
        float EA[4] = {1.f, 1.f, 1.f, 1.f}, EB[4] = {0.f, 0.f, 0.f, 0.f};
        for (int s2 = 0; s2 < w; ++s2) {
            #pragma unroll
            for (int c = 0; c < 4; ++c) {
                float qa = pA_s[s2 * 64 + c * 16 + arow];
                float qb = pB_s[s2 * 64 + c * 16 + arow];
                EB[c] = fmaf(qa, EB[c], qb);
                EA[c] *= qa;
            }
        }
        // per-row chunk-exclusive prefix; 4 rows' (PA,PB) -> one 16B store
        _Float16* prebase = pre + (size_t)cid * 8192;
        #pragma unroll
        for (int c = 0; c < 4; ++c) {
            float pa = eA[c] * EA[c];
            float pb = fmaf(eA[c], EB[c], eB[c]);
            f16x8 sv;
            #pragma unroll
            for (int reg = 0; reg < 4; ++reg) {
                fp16x2 pp = __builtin_amdgcn_cvt_pkrtz(pa, pb);
                sv[2 * reg]     = (_Float16)pp[0];
                sv[2 * reg + 1] = (_Float16)pp[1];
                if (t0 + w * 16 + kb * 4 + reg < NF - 1) {
                    pb = fmaf(a[c][reg], pb, b[c][reg]);
                    pa *= a[c][reg];
                }
            }
            *(f16x8*)&prebase[((((w * 4 + kb) * 4 + c) * 16 + arow) * 4) * 2] = sv;
        }
        // chunk summary -> sA,sB
        if (tid < 64) {
            float At = 1.f, Bt = 0.f;
            #pragma unroll
            for (int s2 = 0; s2 < 4; ++s2) {
                float qa = pA_s[s2 * 64 + tid], qb = pB_s[s2 * 64 + tid];
                Bt = fmaf(qa, Bt, qb);
                At *= qa;
            }
            sA[tid * NC + cid] = At;
            sB[tid * NC + cid] = Bt;
        }
        __syncthreads();   // protect pA_s/pB_s for next iteration
        cid = nxt;
    }
}

// ---------------------------------------------------------------- K3
__global__ __launch_bounds__(256)
void k3_scan(const float* __restrict__ sA, const float* __restrict__ sB,
             float* __restrict__ u0)
{
    __shared__ float tA_s[4], tB_s[4];
    const int j    = blockIdx.x;
    const int lane = threadIdx.x & 63;
    const int w    = threadIdx.x >> 6;

    float PA[GPW], PB[GPW];
    float cA = 1.f, cB = 0.f;
    #pragma unroll
    for (int g = 0; g < GPW; ++g) {
        int c = (w * GPW + g) * 64 + lane;
        float A = 1.f, B = 0.f;
        if (c < NC) { A = sA[j * NC + c]; B = sB[j * NC + c]; }
        #pragma unroll
        for (int d = 1; d < 64; d <<= 1) {
            float pA = __shfl_up(A, d), pB = __shfl_up(B, d);
            if (lane >= d) { B = fmaf(A, pB, B); A *= pA; }
        }
        float eA = __shfl_up(A, 1), eB = __shfl_up(B, 1);
        if (lane == 0) { eA = 1.f; eB = 0.f; }
        PA[g] = eA * cA;
        PB[g] = fmaf(eA, cB, eB);
        float tA = __shfl(A, 63), tB = __shfl(B, 63);
        cB = fmaf(tA, cB, tB);
        cA *= tA;
    }
    if (lane == 0) { tA_s[w] = cA; tB_s[w] = cB; }
    __syncthreads();
    float uw = 0.f;
    for (int s2 = 0; s2 < w; ++s2) uw = fmaf(tA_s[s2], uw, tB_s[s2]);
    #pragma unroll
    for (int g = 0; g < GPW; ++g) {
        int c = (w * GPW + g) * 64 + lane;
        if (c < NC) u0[c * M + j] = fmaf(PA[g], uw, PB[g]);
    }
}

// ---------------------------------------------------------------- K4
__global__ __launch_bounds__(256, 8)
void k4_light(const _Float16* __restrict__ pre, const float* __restrict__ u0,
              const _Float16* __restrict__ wlogpre, const float* __restrict__ bLog,
              float* __restrict__ out)
{
    __shared__ _Float16 z_s[64 * 72];
    const int tid = threadIdx.x, lane = tid & 63, w = tid >> 6;
    const int arow = lane & 15, kb = lane >> 4;
    const int t0 = blockIdx.x * CH;

    float u0v[4];
    #pragma unroll
    for (int c = 0; c < 4; ++c) u0v[c] = u0[blockIdx.x * 64 + c * 16 + arow];

    const _Float16* prebase = pre + (size_t)blockIdx.x * 8192;
    #pragma unroll
    for (int c = 0; c < 4; ++c) {
        f16x8 pv = __builtin_nontemporal_load(
            (const f16x8*)&prebase[((((w * 4 + kb) * 4 + c) * 16 + arow) * 4) * 2]);
        #pragma unroll
        for (int reg = 0; reg < 4; ++reg) {
            int rl = w * 16 + kb * 4 + reg;
            float z = fmaf((float)pv[2 * reg], u0v[c], (float)pv[2 * reg + 1]);
            z_s[rl * 72 + c * 16 + arow] = (_Float16)z;
        }
    }
    __syncthreads();

    f32x4 acc2[4];
    #pragma unroll
    for (int ct = 0; ct < 4; ++ct) acc2[ct] = (f32x4){0.f, 0.f, 0.f, 0.f};
    #pragma unroll
    for (int ks = 0; ks < 2; ++ks) {
        f16x8 af = *(const f16x8*)&z_s[(w * 16 + arow) * 72 + ks * 32 + kb * 8];
        #pragma unroll
        for (int ct = 0; ct < 4; ++ct) {
            f16x8 bf = *(const f16x8*)&wlogpre[((ks * 4 + kb) * 64 + ct * 16 + arow) * 8];
            acc2[ct] = __builtin_amdgcn_mfma_f32_16x16x32_f16(af, bf, acc2[ct], 0, 0, 0);
        }
    }
    #pragma unroll
    for (int ct = 0; ct < 4; ++ct) {
        float bv = bLog[ct * 16 + arow];
        #pragma unroll
        for (int reg = 0; reg < 4; ++reg) {
            int t = t0 + w * 16 + kb * 4 + reg;
            if (t < NF)
                __builtin_nontemporal_store(acc2[ct][reg] + bv,
                                            &out[t * M + ct * 16 + arow]);
        }
    }
}

// ---------------------------------------------------------------- host
extern "C" void kernel_launch(void* const* d_in, const int* in_sizes, int n_in,
                              void* d_out, int out_size, void* d_ws, size_t ws_size,
                              hipStream_t stream)
{
    const float* X    = (const float*)d_in[0];
    const float* WL   = (const float*)d_in[2];
    const float* bL   = (const float*)d_in[3];
    const float* WR   = (const float*)d_in[4];
    const float* bR   = (const float*)d_in[5];
    const float* WLog = (const float*)d_in[6];
    const float* bLog = (const float*)d_in[7];

    // ws layout (~134 MB):
    _Float16* pre = (_Float16*)d_ws;                       // NC*8192 halfs (128 MB)
    float* sA = (float*)((char*)d_ws + (size_t)NC * 8192 * 2);
    float* sB = sA + (size_t)64 * NC;
    float* u0 = sB + (size_t)64 * NC;
    _Float16* wpre    = (_Float16*)(u0 + (size_t)64 * NC); // 16384 halfs
    _Float16* wlogpre = wpre + 16384;                      // 4096 halfs

    k0_pack<<<20, 256, 0, stream>>>(WL, WR, WLog, wpre, wlogpre);
    k1_prefix<<<K1GRID, 256, 0, stream>>>(X, wpre, bL, bR, sA, sB, pre);
    k3_scan<<<M, 256, 0, stream>>>(sA, sB, u0);
    k4_light<<<NC, 256, 0, stream>>>(pre, u0, wlogpre, bLog, (float*)d_out);
}